// Round 15
// baseline (44.658 us; speedup 1.0000x reference)
//
#include <hip/hip_runtime.h>
#include <hip/hip_fp16.h>

#define FEAT 64

typedef _Float16 h2 __attribute__((ext_vector_type(2)));
union HU { uint u; h2 h; };
__device__ inline h2   u2h(uint u) { HU x; x.u = u; return x.h; }
__device__ inline uint h2u(h2 h)   { HU x; x.h = h; return x.u; }
__device__ inline uint packh2f(float lo, float hi) {
    h2 v; v[0] = (_Float16)lo; v[1] = (_Float16)hi; return h2u(v);
}

// 8-feature dot: q holds 8 fp16 (4 x half2), x0..x3 the matching row pairs.
__device__ inline float dot8(uint4 q, h2 x0, h2 x1, h2 x2, h2 x3) {
#if __has_builtin(__builtin_amdgcn_fdot2)
    float d = __builtin_amdgcn_fdot2(u2h(q.x), x0, 0.f, false);
    d = __builtin_amdgcn_fdot2(u2h(q.y), x1, d, false);
    d = __builtin_amdgcn_fdot2(u2h(q.z), x2, d, false);
    d = __builtin_amdgcn_fdot2(u2h(q.w), x3, d, false);
    return d;
#else
    h2 a = u2h(q.x), b = u2h(q.y), c = u2h(q.z), e = u2h(q.w);
    return (float)a[0]*(float)x0[0] + (float)a[1]*(float)x0[1]
         + (float)b[0]*(float)x1[0] + (float)b[1]*(float)x1[1]
         + (float)c[0]*(float)x2[0] + (float)c[1]*(float)x2[1]
         + (float)e[0]*(float)x3[0] + (float)e[1]*(float)x3[1];
#endif
}

// async gather of one 16B/lane row-slice direct to LDS (no VGPR round-trip)
#define GL_LDS(SRC, DST)                                                     \
    __builtin_amdgcn_global_load_lds(                                        \
        (const __attribute__((address_space(1))) void*)(SRC),                \
        (__attribute__((address_space(3))) void*)(DST), 16, 0, 0)

// ---------------------------------------------------------------------------
// prep1: blocks [0,normBlocks): inverse norms rn, raw norms nrm, and the
// NORMALIZED fp16 mirror xhn = fp16(x * rn) (feature-permuted: lane sub
// holds feats [4s,4s+4) and [32+4s,..) in one uint4 = 8 fp16).  Remaining
// blocks: row_ptr build from the SORTED row_index.
// ---------------------------------------------------------------------------
__global__ void prep1_kernel(const float* __restrict__ x,
                             float* __restrict__ rn,
                             float* __restrict__ nrm,
                             uint4* __restrict__ xhn,
                             const int* __restrict__ row,
                             int* __restrict__ row_ptr,
                             int N, int E, int normBlocks) {
    if ((int)blockIdx.x < normBlocks) {
        int wid  = blockIdx.x * (blockDim.x >> 6) + (threadIdx.x >> 6);
        int lane = threadIdx.x & 63;
        int g    = lane >> 3;
        int sub  = lane & 7;
        int r    = wid * 8 + g;
        if (r >= N) return;
        const char* xB = (const char*)x;
        uint roff = ((uint)r << 8) + ((uint)sub << 4);
        float4 xa = *reinterpret_cast<const float4*>(xB + roff);
        float4 xb = *reinterpret_cast<const float4*>(xB + roff + 128);
        float q = xa.x*xa.x + xa.y*xa.y + xa.z*xa.z + xa.w*xa.w
                + xb.x*xb.x + xb.y*xb.y + xb.z*xb.z + xb.w*xb.w;
        q += __shfl_xor(q, 1);
        q += __shfl_xor(q, 2);
        q += __shfl_xor(q, 4);
        float qe  = q + 1e-8f;
        float rnr = rsqrtf(qe);
        if (sub == 0) { rn[r] = rnr; nrm[r] = qe * rnr; }   // nrm = sqrt(qe)
        uint4 p;
        p.x = packh2f(xa.x * rnr, xa.y * rnr);
        p.y = packh2f(xa.z * rnr, xa.w * rnr);
        p.z = packh2f(xb.x * rnr, xb.y * rnr);
        p.w = packh2f(xb.z * rnr, xb.w * rnr);
        xhn[r * 8 + sub] = p;
    } else {
        int e = (blockIdx.x - normBlocks) * blockDim.x + threadIdx.x;
        if (e >= E) return;
        int curr = row[e];
        if (e == 0) {
            for (int r = 0; r <= curr; ++r) row_ptr[r] = 0;
        } else {
            int prev = row[e - 1];
            for (int r = prev + 1; r <= curr; ++r) row_ptr[r] = e;
        }
        if (e == E - 1) {
            for (int r = curr + 1; r <= N; ++r) row_ptr[r] = E;
        }
    }
}

// ---------------------------------------------------------------------------
// prep2: zip[e] = { col[e], bits(nrm[col[e]]) }.
// ---------------------------------------------------------------------------
__global__ void prep2_kernel(const int* __restrict__ col,
                             const float* __restrict__ nrm,
                             int2* __restrict__ zip, int E) {
    int e = blockIdx.x * blockDim.x + threadIdx.x;
    if (e >= E) return;
    int c = col[e];
    zip[e] = make_int2(c, __float_as_int(nrm[c]));
}

// ---------------------------------------------------------------------------
// FUSED attention + shift-free softmax + aggregation, LDS-ring async gathers.
// 8 rows per wave (8-lane group per row).  Per-wave ring of 8 slots x 1KB in
// LDS; global_load_lds streams edge-rows in (8 outstanding, zero VGPR cost),
// manual s_waitcnt vmcnt(4) gates slot readiness; ds_read_b128 (conflict-
// free: consecutive lanes, consecutive 16B) feeds the fp16 dot + packed agg.
// ---------------------------------------------------------------------------
__global__ void fused_kernel(const float* __restrict__ x,
                             const uint4* __restrict__ xhn,
                             const float* __restrict__ rn,
                             const float* __restrict__ beta,
                             const int* __restrict__ row_ptr,
                             const int2* __restrict__ zip,
                             float* __restrict__ out, int N) {
    __shared__ uint4 ring[4][8][64];    // [wave][slot][lane] = 32 KB
    int wv   = threadIdx.x >> 6;
    int lane = threadIdx.x & 63;
    int g    = lane >> 3;               // group = row slot (0..7)
    int sub  = lane & 7;
    int wid  = blockIdx.x * 4 + wv;
    int r    = wid * 8 + g;
    bool rv  = (r < N);

    int start = 0, deg = 0;
    if (rv) {
        start = row_ptr[r];
        deg   = row_ptr[r + 1] - start;
    }

    // x_r scaled by beta*rn_r, converted to 4 half2 pairs
    h2 xr0, xr1, xr2, xr3;
    {
        float4 xa = make_float4(0.f, 0.f, 0.f, 0.f);
        float4 xb = make_float4(0.f, 0.f, 0.f, 0.f);
        if (rv) {
            const char* xB = (const char*)x;
            uint roff = ((uint)r << 8) + ((uint)sub << 4);
            xa = *reinterpret_cast<const float4*>(xB + roff);
            xb = *reinterpret_cast<const float4*>(xB + roff + 128);
            float brn = beta[0] * rn[r];
            xa.x *= brn; xa.y *= brn; xa.z *= brn; xa.w *= brn;
            xb.x *= brn; xb.y *= brn; xb.z *= brn; xb.w *= brn;
        }
        xr0 = u2h(packh2f(xa.x, xa.y));
        xr1 = u2h(packh2f(xa.z, xa.w));
        xr2 = u2h(packh2f(xb.x, xb.y));
        xr3 = u2h(packh2f(xb.z, xb.w));
    }

    // zip chunks: A = edges [a, a+8), B = [a+8, a+16)   (zero-init = safe:
    // col 0 is a valid dummy row, masked later by e=0)
    int2 zipA = make_int2(0, 0), zipB = make_int2(0, 0);
    if (sub < deg)     zipA = zip[start + sub];
    if (8 + sub < deg) zipB = zip[start + 8 + sub];

    // prologue: issue edges 0..7 into slots 0..7 (always 8, wave-uniform)
    #pragma unroll
    for (int j = 0; j < 8; ++j) {
        int cj = __shfl(zipA.x, j, 8);
        GL_LDS(xhn + (uint)cj * 8u + sub, &ring[wv][j][0]);
    }

    float  s  = 0.f;
    float4 aa = make_float4(0.f, 0.f, 0.f, 0.f);
    float4 ab = make_float4(0.f, 0.f, 0.f, 0.f);

    for (int base = 0; base < deg; base += 4) {
        // gate: slots base..base+3 written (allow newest 4 loads in flight)
        asm volatile("s_waitcnt vmcnt(4)" ::: "memory");
        int s0 = base & 7;
        uint4 q0 = ring[wv][s0 + 0][lane];
        uint4 q1 = ring[wv][s0 + 1][lane];
        uint4 q2 = ring[wv][s0 + 2][lane];
        uint4 q3 = ring[wv][s0 + 3][lane];
        // slots must be fully read before re-issue overwrites them
        asm volatile("s_waitcnt lgkmcnt(0)" ::: "memory");

        // rotate zip chunks at 8-boundaries; refill B
        if (base && s0 == 0) {
            zipA = zipB;
            zipB = make_int2(0, 0);
            if (base + 8 + sub < deg) zipB = zip[start + base + 8 + sub];
        }

        // norms for this quad (chunk A, kk = base&7 .. +3)
        float n0 = __shfl(__int_as_float(zipA.y), s0 + 0, 8);
        float n1 = __shfl(__int_as_float(zipA.y), s0 + 1, 8);
        float n2 = __shfl(__int_as_float(zipA.y), s0 + 2, 8);
        float n3 = __shfl(__int_as_float(zipA.y), s0 + 3, 8);

        // issue edges base+8..base+11 (always chunk B, kk = base&7) into the
        // just-freed slots
        {
            int c0n = __shfl(zipB.x, s0 + 0, 8);
            int c1n = __shfl(zipB.x, s0 + 1, 8);
            int c2n = __shfl(zipB.x, s0 + 2, 8);
            int c3n = __shfl(zipB.x, s0 + 3, 8);
            GL_LDS(xhn + (uint)c0n * 8u + sub, &ring[wv][s0 + 0][0]);
            GL_LDS(xhn + (uint)c1n * 8u + sub, &ring[wv][s0 + 1][0]);
            GL_LDS(xhn + (uint)c2n * 8u + sub, &ring[wv][s0 + 2][0]);
            GL_LDS(xhn + (uint)c3n * 8u + sub, &ring[wv][s0 + 3][0]);
        }

        // ---- dots (fp16 hw dot, fp32 accumulate) ----
        float d0 = dot8(q0, xr0, xr1, xr2, xr3);
        float d1 = dot8(q1, xr0, xr1, xr2, xr3);
        float d2 = dot8(q2, xr0, xr1, xr2, xr3);
        float d3 = dot8(q3, xr0, xr1, xr2, xr3);
        d0 += __shfl_xor(d0, 1);  d1 += __shfl_xor(d1, 1);
        d2 += __shfl_xor(d2, 1);  d3 += __shfl_xor(d3, 1);
        d0 += __shfl_xor(d0, 2);  d1 += __shfl_xor(d1, 2);
        d2 += __shfl_xor(d2, 2);  d3 += __shfl_xor(d3, 2);
        d0 += __shfl_xor(d0, 4);  d1 += __shfl_xor(d1, 4);
        d2 += __shfl_xor(d2, 4);  d3 += __shfl_xor(d3, 4);

        float e0 = (base + 0 < deg) ? __expf(d0) : 0.f;  // att bounded by |beta|
        float e1 = (base + 1 < deg) ? __expf(d1) : 0.f;
        float e2 = (base + 2 < deg) ? __expf(d2) : 0.f;
        float e3 = (base + 3 < deg) ? __expf(d3) : 0.f;
        s += (e0 + e1) + (e2 + e3);

        // ---- packed fp16 aggregation, per-quad partials ----
        float w0 = e0 * n0, w1 = e1 * n1, w2 = e2 * n2, w3 = e3 * n3;
        h2 wh0; wh0[0] = (_Float16)w0; wh0[1] = wh0[0];
        h2 wh1; wh1[0] = (_Float16)w1; wh1[1] = wh1[0];
        h2 wh2; wh2[0] = (_Float16)w2; wh2[1] = wh2[0];
        h2 wh3; wh3[0] = (_Float16)w3; wh3[1] = wh3[0];

        h2 p0 = u2h(q0.x) * wh0;  p0 = u2h(q1.x) * wh1 + p0;
        p0 = u2h(q2.x) * wh2 + p0;  p0 = u2h(q3.x) * wh3 + p0;
        h2 p1 = u2h(q0.y) * wh0;  p1 = u2h(q1.y) * wh1 + p1;
        p1 = u2h(q2.y) * wh2 + p1;  p1 = u2h(q3.y) * wh3 + p1;
        h2 p2 = u2h(q0.z) * wh0;  p2 = u2h(q1.z) * wh1 + p2;
        p2 = u2h(q2.z) * wh2 + p2;  p2 = u2h(q3.z) * wh3 + p2;
        h2 p3 = u2h(q0.w) * wh0;  p3 = u2h(q1.w) * wh1 + p3;
        p3 = u2h(q2.w) * wh2 + p3;  p3 = u2h(q3.w) * wh3 + p3;

        aa.x += (float)p0[0];  aa.y += (float)p0[1];
        aa.z += (float)p1[0];  aa.w += (float)p1[1];
        ab.x += (float)p2[0];  ab.y += (float)p2[1];
        ab.z += (float)p3[0];  ab.w += (float)p3[1];
    }

    // drain all outstanding LDS-writes before wave retire (LDS realloc hazard)
    asm volatile("s_waitcnt vmcnt(0)" ::: "memory");

    float inv = 1.0f / fmaxf(s, 1e-16f);      // deg==0 -> out = 0
    if (rv) {
        uint roff = ((uint)r << 8) + ((uint)sub << 4);
        *reinterpret_cast<float4*>((char*)out + roff) =
            make_float4(aa.x * inv, aa.y * inv, aa.z * inv, aa.w * inv);
        *reinterpret_cast<float4*>((char*)out + roff + 128) =
            make_float4(ab.x * inv, ab.y * inv, ab.z * inv, ab.w * inv);
    }
}

// ---------------------------------------------------------------------------
extern "C" void kernel_launch(void* const* d_in, const int* in_sizes, int n_in,
                              void* d_out, int out_size, void* d_ws, size_t ws_size,
                              hipStream_t stream) {
    const float* x    = (const float*)d_in[0];
    const float* beta = (const float*)d_in[1];
    const int*   row  = (const int*)d_in[2];
    const int*   col  = (const int*)d_in[3];
    float*       out  = (float*)d_out;

    const int N = in_sizes[0] / FEAT;   // 50000
    const int E = in_sizes[2];          // 800000

    // Workspace layout (512B-aligned chunks):
    // rn[N] | nrm[N] | row_ptr[N+1] | zip[E] int2 | xhn[N*8 uint4]
    char*  ws = (char*)d_ws;
    size_t o  = 0;
    auto alloc = [&](size_t bytes) {
        size_t cur = o;
        o = (o + bytes + 511) & ~(size_t)511;
        return cur;
    };
    float* rn      = (float*)(ws + alloc((size_t)N * 4));
    float* nrm     = (float*)(ws + alloc((size_t)N * 4));
    int*   row_ptr = (int*)  (ws + alloc((size_t)(N + 1) * 4));
    int2*  zip     = (int2*) (ws + alloc((size_t)E * 8));
    uint4* xhn     = (uint4*)(ws + alloc((size_t)N * 128));

    {   // prep1: norms + normalized fp16 mirror + rowptr
        int normBlocks = (N + 31) / 32;
        int edgeBlocks = (E + 255) / 256;
        prep1_kernel<<<normBlocks + edgeBlocks, 256, 0, stream>>>(
            x, rn, nrm, xhn, row, row_ptr, N, E, normBlocks);
    }
    {   // prep2: zip col+nrm per edge
        int grid = (E + 255) / 256;
        prep2_kernel<<<grid, 256, 0, stream>>>(col, nrm, zip, E);
    }
    {   // fused: 8 rows per wave, 4 waves per block, LDS-ring pipeline
        int waves = (N + 7) / 8;
        int grid  = (waves + 3) / 4;
        fused_kernel<<<grid, 256, 0, stream>>>(
            x, xhn, rn, beta, row_ptr, zip, out, N);
    }
}

// Round 16
// 38.305 us; speedup vs baseline: 1.1659x; 1.1659x over previous
//
#include <hip/hip_runtime.h>
#include <hip/hip_bf16.h>

#define FEAT 64

// RNE pack of two fp32 into one u32 of 2 bf16 (lo, hi)
__device__ inline uint packbf2(float lo, float hi) {
    uint ul = __float_as_uint(lo), uh = __float_as_uint(hi);
    ul += 0x7FFFu + ((ul >> 16) & 1u);
    uh += 0x7FFFu + ((uh >> 16) & 1u);
    return (ul >> 16) | (uh & 0xFFFF0000u);
}

// unpack uint4 (8 bf16) -> two float4
__device__ inline void unpack8(uint4 q, float4& va, float4& vb) {
    va.x = __uint_as_float(q.x << 16);
    va.y = __uint_as_float(q.x & 0xFFFF0000u);
    va.z = __uint_as_float(q.y << 16);
    va.w = __uint_as_float(q.y & 0xFFFF0000u);
    vb.x = __uint_as_float(q.z << 16);
    vb.y = __uint_as_float(q.z & 0xFFFF0000u);
    vb.z = __uint_as_float(q.w << 16);
    vb.w = __uint_as_float(q.w & 0xFFFF0000u);
}

// ---------------------------------------------------------------------------
// Kernel 1 (merged prep): blocks [0, normBlocks): inverse L2 norms + bf16
// mirror of x (feature-permuted so lane sub holds features [4s,4s+4) and
// [32+4s,32+4s+4) in one uint4).  Remaining blocks: row_ptr[N+1] build from
// the SORTED row_index.
// ---------------------------------------------------------------------------
__global__ void prep_kernel(const float* __restrict__ x,
                            float* __restrict__ rn,
                            uint4* __restrict__ xh,      // may be null
                            const int* __restrict__ row,
                            int* __restrict__ row_ptr,
                            int N, int E, int normBlocks) {
    if ((int)blockIdx.x < normBlocks) {
        int wid  = blockIdx.x * (blockDim.x >> 6) + (threadIdx.x >> 6);
        int lane = threadIdx.x & 63;
        int g    = lane >> 3;
        int sub  = lane & 7;
        int r    = wid * 8 + g;
        if (r >= N) return;
        const char* xB = (const char*)x;
        uint roff = ((uint)r << 8) + ((uint)sub << 4);
        float4 xa = *reinterpret_cast<const float4*>(xB + roff);
        float4 xb = *reinterpret_cast<const float4*>(xB + roff + 128);
        float q = xa.x*xa.x + xa.y*xa.y + xa.z*xa.z + xa.w*xa.w
                + xb.x*xb.x + xb.y*xb.y + xb.z*xb.z + xb.w*xb.w;
        q += __shfl_xor(q, 1);
        q += __shfl_xor(q, 2);
        q += __shfl_xor(q, 4);
        if (sub == 0) rn[r] = rsqrtf(q + 1e-8f);
        if (xh) {
            uint4 p;
            p.x = packbf2(xa.x, xa.y);
            p.y = packbf2(xa.z, xa.w);
            p.z = packbf2(xb.x, xb.y);
            p.w = packbf2(xb.z, xb.w);
            xh[r * 8 + sub] = p;
        }
    } else {
        int e = (blockIdx.x - normBlocks) * blockDim.x + threadIdx.x;
        if (e >= E) return;
        int curr = row[e];
        if (e == 0) {
            for (int r = 0; r <= curr; ++r) row_ptr[r] = 0;
        } else {
            int prev = row[e - 1];
            for (int r = prev + 1; r <= curr; ++r) row_ptr[r] = e;
        }
        if (e == E - 1) {
            for (int r = curr + 1; r <= N; ++r) row_ptr[r] = E;
        }
    }
}

// ---------------------------------------------------------------------------
// Kernel 2: FUSED attention + shift-free softmax + aggregation, bf16 gathers.
// One 8-lane group per row, 8 rows per wave.  Per edge: ONE dwordx4 gather
// (128B bf16 row), unpack, 8-FMA dot, 3-shfl reduce, exp, 8-FMA accumulate.
// 4-edge software pipeline: loads for edges k+4..k+7 are issued before
// processing k..k+3 (col/rn chunks double-buffered 8 ahead), keeping >=4
// independent gathers in flight per wave.
// ---------------------------------------------------------------------------
__global__ void fused_bf16_kernel(const float* __restrict__ x,
                                  const uint4* __restrict__ xh,
                                  const float* __restrict__ rn,
                                  const float* __restrict__ beta,
                                  const int* __restrict__ row_ptr,
                                  const int* __restrict__ col,
                                  float* __restrict__ out, int N) {
    int wid  = blockIdx.x * (blockDim.x >> 6) + (threadIdx.x >> 6);
    int lane = threadIdx.x & 63;
    int g    = lane >> 3;               // group = row slot (0..7)
    int sub  = lane & 7;
    int r    = wid * 8 + g;
    bool rv  = (r < N);

    int start = 0, deg = 0;
    if (rv) {
        start = row_ptr[r];
        deg   = row_ptr[r + 1] - start;
    }

    // col/rn chunks: A = edges [a, a+8), B = [a+8, a+16)
    int   colsA = 0, colsB = 0;
    float rnsA  = 0.f, rnsB = 0.f;
    if (sub < deg)     { colsA = col[start + sub];     rnsA = rn[colsA]; }
    if (8 + sub < deg) { colsB = col[start + 8 + sub]; rnsB = rn[colsB]; }

    // x_r fp32, scaled by beta*rn_r:  att = (beta*rn_r*x_r) . x_c * rn_c
    float4 xa = make_float4(0.f, 0.f, 0.f, 0.f);
    float4 xb = make_float4(0.f, 0.f, 0.f, 0.f);
    if (rv) {
        const char* xB = (const char*)x;
        uint roff = ((uint)r << 8) + ((uint)sub << 4);
        xa = *reinterpret_cast<const float4*>(xB + roff);
        xb = *reinterpret_cast<const float4*>(xB + roff + 128);
        float brn = beta[0] * rn[r];
        xa.x *= brn; xa.y *= brn; xa.z *= brn; xa.w *= brn;
        xb.x *= brn; xb.y *= brn; xb.z *= brn; xb.w *= brn;
    }

    float  s  = 0.f;
    float4 aa = make_float4(0.f, 0.f, 0.f, 0.f);
    float4 ab = make_float4(0.f, 0.f, 0.f, 0.f);

    uint4 z4 = make_uint4(0u, 0u, 0u, 0u);
    uint4 q0 = z4, q1 = z4, q2 = z4, q3 = z4;
    float rn0 = 0.f, rn1 = 0.f, rn2 = 0.f, rn3 = 0.f;

    // prologue: fetch edges 0..3 (chunk A, kk 0..3)
    {
        int   c0 = __shfl(colsA, 0, 8), c1 = __shfl(colsA, 1, 8);
        int   c2 = __shfl(colsA, 2, 8), c3 = __shfl(colsA, 3, 8);
        rn0 = __shfl(rnsA, 0, 8);  rn1 = __shfl(rnsA, 1, 8);
        rn2 = __shfl(rnsA, 2, 8);  rn3 = __shfl(rnsA, 3, 8);
        if (0 < deg) q0 = xh[c0 * 8 + sub];
        if (1 < deg) q1 = xh[c1 * 8 + sub];
        if (2 < deg) q2 = xh[c2 * 8 + sub];
        if (3 < deg) q3 = xh[c3 * 8 + sub];
    }

    for (int base = 0; base < deg; base += 4) {
        // rotate chunks at 8-boundaries; refill B two iterations ahead
        if (base && (base & 7) == 0) {
            colsA = colsB;  rnsA = rnsB;
            colsB = 0;      rnsB = 0.f;
            if (base + 8 + sub < deg) {
                colsB = col[start + base + 8 + sub];
                rnsB  = rn[colsB];
            }
        }
        // issue loads for next quad (edges base+4..base+7)
        int  nb  = base + 4;
        int  nkk = nb & 7;                       // 4 -> in A, 0 -> in B
        int   cS = (nkk == 4) ? colsA : colsB;
        float rS = (nkk == 4) ? rnsA  : rnsB;
        int   nc0 = __shfl(cS, nkk + 0, 8), nc1 = __shfl(cS, nkk + 1, 8);
        int   nc2 = __shfl(cS, nkk + 2, 8), nc3 = __shfl(cS, nkk + 3, 8);
        float nr0 = __shfl(rS, nkk + 0, 8), nr1 = __shfl(rS, nkk + 1, 8);
        float nr2 = __shfl(rS, nkk + 2, 8), nr3 = __shfl(rS, nkk + 3, 8);
        uint4 nq0 = z4, nq1 = z4, nq2 = z4, nq3 = z4;
        if (nb + 0 < deg) nq0 = xh[nc0 * 8 + sub];
        if (nb + 1 < deg) nq1 = xh[nc1 * 8 + sub];
        if (nb + 2 < deg) nq2 = xh[nc2 * 8 + sub];
        if (nb + 3 < deg) nq3 = xh[nc3 * 8 + sub];

        // process current quad
        float4 va0, vb0, va1, vb1, va2, vb2, va3, vb3;
        unpack8(q0, va0, vb0);  unpack8(q1, va1, vb1);
        unpack8(q2, va2, vb2);  unpack8(q3, va3, vb3);

        float d0 = xa.x*va0.x + xa.y*va0.y + xa.z*va0.z + xa.w*va0.w
                 + xb.x*vb0.x + xb.y*vb0.y + xb.z*vb0.z + xb.w*vb0.w;
        float d1 = xa.x*va1.x + xa.y*va1.y + xa.z*va1.z + xa.w*va1.w
                 + xb.x*vb1.x + xb.y*vb1.y + xb.z*vb1.z + xb.w*vb1.w;
        float d2 = xa.x*va2.x + xa.y*va2.y + xa.z*va2.z + xa.w*va2.w
                 + xb.x*vb2.x + xb.y*vb2.y + xb.z*vb2.z + xb.w*vb2.w;
        float d3 = xa.x*va3.x + xa.y*va3.y + xa.z*va3.z + xa.w*va3.w
                 + xb.x*vb3.x + xb.y*vb3.y + xb.z*vb3.z + xb.w*vb3.w;
        d0 += __shfl_xor(d0, 1);  d1 += __shfl_xor(d1, 1);
        d2 += __shfl_xor(d2, 1);  d3 += __shfl_xor(d3, 1);
        d0 += __shfl_xor(d0, 2);  d1 += __shfl_xor(d1, 2);
        d2 += __shfl_xor(d2, 2);  d3 += __shfl_xor(d3, 2);
        d0 += __shfl_xor(d0, 4);  d1 += __shfl_xor(d1, 4);
        d2 += __shfl_xor(d2, 4);  d3 += __shfl_xor(d3, 4);

        float e0 = (base + 0 < deg) ? __expf(d0 * rn0) : 0.f;
        float e1 = (base + 1 < deg) ? __expf(d1 * rn1) : 0.f;
        float e2 = (base + 2 < deg) ? __expf(d2 * rn2) : 0.f;
        float e3 = (base + 3 < deg) ? __expf(d3 * rn3) : 0.f;
        s += (e0 + e1) + (e2 + e3);

        aa.x += e0*va0.x + e1*va1.x + e2*va2.x + e3*va3.x;
        aa.y += e0*va0.y + e1*va1.y + e2*va2.y + e3*va3.y;
        aa.z += e0*va0.z + e1*va1.z + e2*va2.z + e3*va3.z;
        aa.w += e0*va0.w + e1*va1.w + e2*va2.w + e3*va3.w;
        ab.x += e0*vb0.x + e1*vb1.x + e2*vb2.x + e3*vb3.x;
        ab.y += e0*vb0.y + e1*vb1.y + e2*vb2.y + e3*vb3.y;
        ab.z += e0*vb0.z + e1*vb1.z + e2*vb2.z + e3*vb3.z;
        ab.w += e0*vb0.w + e1*vb1.w + e2*vb2.w + e3*vb3.w;

        q0 = nq0; q1 = nq1; q2 = nq2; q3 = nq3;
        rn0 = nr0; rn1 = nr1; rn2 = nr2; rn3 = nr3;
    }

    float inv = 1.0f / fmaxf(s, 1e-16f);      // deg==0 -> out = 0
    if (rv) {
        uint roff = ((uint)r << 8) + ((uint)sub << 4);
        *reinterpret_cast<float4*>((char*)out + roff) =
            make_float4(aa.x * inv, aa.y * inv, aa.z * inv, aa.w * inv);
        *reinterpret_cast<float4*>((char*)out + roff + 128) =
            make_float4(ab.x * inv, ab.y * inv, ab.z * inv, ab.w * inv);
    }
}

// ---------------------------------------------------------------------------
// Fallback (fp32 gathers) if workspace can't hold the bf16 mirror.
// ---------------------------------------------------------------------------
__global__ void fused_kernel(const float* __restrict__ x,
                             const float* __restrict__ rn,
                             const float* __restrict__ beta,
                             const int* __restrict__ row_ptr,
                             const int* __restrict__ col,
                             float* __restrict__ out, int N) {
    int wid  = blockIdx.x * (blockDim.x >> 6) + (threadIdx.x >> 6);
    int lane = threadIdx.x & 63;
    int slot = lane >> 4;
    int h    = (lane >> 3) & 1;
    int sub  = lane & 7;
    int r    = wid * 4 + slot;
    bool rv  = (r < N);

    int start = 0, deg = 0;
    if (rv) {
        start = row_ptr[r];
        deg   = row_ptr[r + 1] - start;
    }

    const char* xB   = (const char*)x;
    uint        subo = (uint)sub << 4;

    int   colsA = 0, colsB = 0;
    float rnsA  = 0.f, rnsB = 0.f;
    if (sub < deg)     { colsA = col[start + sub];     rnsA = rn[colsA]; }
    if (8 + sub < deg) { colsB = col[start + 8 + sub]; rnsB = rn[colsB]; }

    float4 xa = make_float4(0.f, 0.f, 0.f, 0.f);
    float4 xb = make_float4(0.f, 0.f, 0.f, 0.f);
    if (rv) {
        uint roff = ((uint)r << 8) + subo;
        xa = *reinterpret_cast<const float4*>(xB + roff);
        xb = *reinterpret_cast<const float4*>(xB + roff + 128);
        float brn = beta[0] * rn[r];
        xa.x *= brn; xa.y *= brn; xa.z *= brn; xa.w *= brn;
        xb.x *= brn; xb.y *= brn; xb.z *= brn; xb.w *= brn;
    }

    float  s = 0.f;
    float4 aa = make_float4(0.f, 0.f, 0.f, 0.f);
    float4 ab = make_float4(0.f, 0.f, 0.f, 0.f);

    for (int base = 0; base < deg; base += 4) {
        if (base && (base & 7) == 0) {
            colsA = colsB;  rnsA = rnsB;
            if (base + 8 + sub < deg) {
                colsB = col[start + base + 8 + sub];
                rnsB  = rn[colsB];
            }
        }
        int  k0 = base + 2 * h;
        int  kk = (base & 7) + 2 * h;
        bool v0 = k0 < deg;
        bool v1 = k0 + 1 < deg;

        int   c0  = __shfl(colsA, kk, 8);
        float rw0 = __shfl(rnsA,  kk, 8);
        int   c1  = __shfl(colsA, kk + 1, 8);
        float rw1 = __shfl(rnsA,  kk + 1, 8);

        float4 va0 = make_float4(0.f, 0.f, 0.f, 0.f);
        float4 vb0 = make_float4(0.f, 0.f, 0.f, 0.f);
        float4 va1 = make_float4(0.f, 0.f, 0.f, 0.f);
        float4 vb1 = make_float4(0.f, 0.f, 0.f, 0.f);
        if (v0) {
            uint o0 = ((uint)c0 << 8) + subo;
            va0 = *reinterpret_cast<const float4*>(xB + o0);
            vb0 = *reinterpret_cast<const float4*>(xB + o0 + 128);
        }
        if (v1) {
            uint o1 = ((uint)c1 << 8) + subo;
            va1 = *reinterpret_cast<const float4*>(xB + o1);
            vb1 = *reinterpret_cast<const float4*>(xB + o1 + 128);
        }

        float d0 = xa.x*va0.x + xa.y*va0.y + xa.z*va0.z + xa.w*va0.w
                 + xb.x*vb0.x + xb.y*vb0.y + xb.z*vb0.z + xb.w*vb0.w;
        float d1 = xa.x*va1.x + xa.y*va1.y + xa.z*va1.z + xa.w*va1.w
                 + xb.x*vb1.x + xb.y*vb1.y + xb.z*vb1.z + xb.w*vb1.w;
        d0 += __shfl_xor(d0, 1);  d1 += __shfl_xor(d1, 1);
        d0 += __shfl_xor(d0, 2);  d1 += __shfl_xor(d1, 2);
        d0 += __shfl_xor(d0, 4);  d1 += __shfl_xor(d1, 4);

        float e0 = v0 ? __expf(d0 * rw0) : 0.f;
        float e1 = v1 ? __expf(d1 * rw1) : 0.f;
        s += e0 + e1;

        aa.x += e0 * va0.x + e1 * va1.x;  aa.y += e0 * va0.y + e1 * va1.y;
        aa.z += e0 * va0.z + e1 * va1.z;  aa.w += e0 * va0.w + e1 * va1.w;
        ab.x += e0 * vb0.x + e1 * vb1.x;  ab.y += e0 * vb0.y + e1 * vb1.y;
        ab.z += e0 * vb0.z + e1 * vb1.z;  ab.w += e0 * vb0.w + e1 * vb1.w;
    }

    s    += __shfl_xor(s, 8);
    aa.x += __shfl_xor(aa.x, 8);  aa.y += __shfl_xor(aa.y, 8);
    aa.z += __shfl_xor(aa.z, 8);  aa.w += __shfl_xor(aa.w, 8);
    ab.x += __shfl_xor(ab.x, 8);  ab.y += __shfl_xor(ab.y, 8);
    ab.z += __shfl_xor(ab.z, 8);  ab.w += __shfl_xor(ab.w, 8);

    float inv = 1.0f / fmaxf(s, 1e-16f);
    if (rv) {
        float4 o = h ? ab : aa;
        uint roff = ((uint)r << 8) + subo + ((uint)h << 7);
        *reinterpret_cast<float4*>((char*)out + roff) =
            make_float4(o.x * inv, o.y * inv, o.z * inv, o.w * inv);
    }
}

// ---------------------------------------------------------------------------
extern "C" void kernel_launch(void* const* d_in, const int* in_sizes, int n_in,
                              void* d_out, int out_size, void* d_ws, size_t ws_size,
                              hipStream_t stream) {
    const float* x    = (const float*)d_in[0];
    const float* beta = (const float*)d_in[1];
    const int*   row  = (const int*)d_in[2];
    const int*   col  = (const int*)d_in[3];
    float*       out  = (float*)d_out;

    const int N = in_sizes[0] / FEAT;   // 50000
    const int E = in_sizes[2];          // 800000

    // Workspace layout: rn[N] | row_ptr[N+1] | xh[N*64 bf16]  (512B-aligned)
    char*  ws      = (char*)d_ws;
    size_t off_rp  = ((size_t)(N + 64) * 4 + 511) & ~(size_t)511;
    size_t off_xh  = off_rp + (((size_t)(N + 1) * 4 + 511) & ~(size_t)511);
    size_t need    = off_xh + (size_t)N * 128;

    float* rn      = (float*)ws;
    int*   row_ptr = (int*)(ws + off_rp);
    uint4* xh      = (ws_size >= need) ? (uint4*)(ws + off_xh) : nullptr;

    {   // merged prep: norms (+ bf16 mirror) + rowptr build
        int normBlocks = (N + 31) / 32;
        int edgeBlocks = (E + 255) / 256;
        prep_kernel<<<normBlocks + edgeBlocks, 256, 0, stream>>>(
            x, rn, xh, row, row_ptr, N, E, normBlocks);
    }
    if (xh) {   // bf16-gather fused: 8 rows/wave, 4 waves/block
        int waves = (N + 7) / 8;
        int grid  = (waves + 3) / 4;
        fused_bf16_kernel<<<grid, 256, 0, stream>>>(
            x, xh, rn, beta, row_ptr, col, out, N);
    } else {    // fp32 fallback: 4 rows/wave (2 groups/row)
        int waves = (N + 3) / 4;
        int grid  = (waves + 3) / 4;
        fused_kernel<<<grid, 256, 0, stream>>>(
            x, rn, beta, row_ptr, col, out, N);
    }
}